// Round 8
// baseline (209.395 us; speedup 1.0000x reference)
//
#include <hip/hip_runtime.h>
#include <math.h>

#define SEGS 14            // segments per row
#define SLEN 9             // steps per segment; 14*9 = 126, 9 % 3 == 0
#define RPB  32            // rows per block
#define TPB  (RPB * SEGS)  // 448 threads = 7 waves
#define INF  (TPB * 18)    // 8064 staged input floats  (32 rows x 252)
#define STF  (TPB * 27)    // 12096 staged output floats (32 rows x 378)

// 1/max(sqrt(x),1e-12) == rsqrt(max(x,1e-24)); rsq ~1 ulp.
__device__ __forceinline__ float grsq(float x) {
    return __builtin_amdgcn_rsqf(fmaxf(x, 1e-24f));
}

__global__ __launch_bounds__(TPB, 5) void DihedralToCartesian_kernel(
    const float* __restrict__ angles,   // (B, 252): [0:126)=sin, [126:252)=cos
    const float* __restrict__ prev,     // (B, 3, 3)
    float* __restrict__ out,            // (B, 126, 3)
    int nrows)
{
    // One buffer, three lives: IN (8064 f) -> E scan slots (448*13 f) -> ST (12096 f)
    __shared__ float buf[STF];          // 48.4 KB
    __shared__ float F0[RPB][13];       // 1.7 KB

    if (blockIdx.x * RPB >= nrows) return;   // uniform, never taken (exact grid)

    const int t  = threadIdx.x;
    const int s  = t % SEGS;
    const int rl = t / SEGS;
    const size_t gin  = (size_t)blockIdx.x * (RPB * 252);
    const size_t gout = (size_t)blockIdx.x * (RPB * 378);

    // ---- stage inputs: block-dense, fully coalesced ----
    #pragma unroll
    for (int i = 0; i < 18; ++i)
        buf[i * TPB + t] = angles[gin + i * TPB + t];

    // ---- F0 from prev_three (one lane per row), exactly per reference ----
    if (s == 0) {
        const float* pr = prev + (size_t)(blockIdx.x * RPB + rl) * 9;
        float a0=pr[0],a1=pr[1],a2=pr[2];
        float b0=pr[3],b1=pr[4],b2=pr[5];
        float c0=pr[6],c1=pr[7],c2=pr[8];
        float ux=b0-c0+1e-8f, uy=b1-c1+1e-8f, uz=b2-c2+1e-8f;
        float ru=grsq(ux*ux+uy*uy+uz*uz); ux*=ru; uy*=ru; uz*=ru;
        float vx=b0-a0, vy=b1-a1, vz=b2-a2;
        float nx=vy*uz-vz*uy+1e-8f, ny=vz*ux-vx*uz+1e-8f, nz=vx*uy-vy*ux+1e-8f;
        float rn=grsq(nx*nx+ny*ny+nz*nz); nx*=rn; ny*=rn; nz*=rn;
        float mx=ny*uz-nz*uy, my=nz*ux-nx*uz, mz=nx*uy-ny*ux;
        float* f = F0[rl];              // R cols = [bc | m1 | n], t = c
        f[0]=ux; f[1]=mx; f[2]=nx;
        f[3]=uy; f[4]=my; f[5]=ny;
        f[6]=uz; f[7]=mz; f[8]=nz;
        f[9]=c0; f[10]=c1; f[11]=c2;
    }

    __syncthreads();   // IN slab ready

    // ---- pull own segment's 9 sin + 9 cos into registers ----
    float sn[SLEN], cs[SLEN];
    {
        const float* myin = buf + rl * 252 + s * SLEN;
        #pragma unroll
        for (int j = 0; j < SLEN; ++j) { sn[j] = myin[j]; cs[j] = myin[126 + j]; }
    }

    __syncthreads();   // IN consumed; buf free for E

    // 3-periodic constants (compile-time folded); step phase = j % 3 (SLEN%3==0)
    const float ca0=cosf(2.028f), sa0=sinf(2.028f), bc0=1.329f*ca0, bs0=1.329f*sa0;
    const float ca1=cosf(2.124f), sa1=sinf(2.124f), bc1=1.458f*ca1, bs1=1.458f*sa1;
    const float ca2=cosf(1.941f), sa2=sinf(1.941f), bc2=1.523f*ca2, bs2=1.523f*sa2;

    // ---- phase 1: compose segment transform S_s = A_0 * ... * A_8 (regs only) ----
    float r0,r1,r2,r3,r4,r5,r6,r7,r8, tx,ty,tz;
    #pragma unroll
    for (int j = 0; j < SLEN; ++j) {
        const int ph = j % 3;
        const float ca  = (ph==0)?ca0:(ph==1)?ca1:ca2;
        const float sa  = (ph==0)?sa0:(ph==1)?sa1:sa2;
        const float bca = (ph==0)?bc0:(ph==1)?bc1:bc2;
        const float bsa = (ph==0)?bs0:(ph==1)?bs1:bs2;

        float rr = __builtin_amdgcn_rsqf(sn[j]*sn[j] + cs[j]*cs[j] + 1e-8f);
        float st = sn[j]*rr, ct = cs[j]*rr;
        float m10=-sa*ct, m11=-ca*ct, m20=sa*st, m21=ca*st;
        float tl1=bsa*ct, tl2=-bsa*st;

        if (j == 0) {
            r0=-ca;  r1=sa;   r2=0.f;
            r3=m10;  r4=m11;  r5=st;
            r6=m20;  r7=m21;  r8=ct;
            tx=bca;  ty=tl1;  tz=tl2;
        } else {
            float q0 = tx + r0*bca + r1*tl1 + r2*tl2;
            float q1 = ty + r3*bca + r4*tl1 + r5*tl2;
            float q2 = tz + r6*bca + r7*tl1 + r8*tl2;
            float n0 = r0*(-ca) + r1*m10 + r2*m20;
            float n1 = r0*sa    + r1*m11 + r2*m21;
            float n2 =            r1*st  + r2*ct;
            float n3 = r3*(-ca) + r4*m10 + r5*m20;
            float n4 = r3*sa    + r4*m11 + r5*m21;
            float n5 =            r4*st  + r5*ct;
            float n6 = r6*(-ca) + r7*m10 + r8*m20;
            float n7 = r6*sa    + r7*m11 + r8*m21;
            float n8 =            r7*st  + r8*ct;
            r0=n0; r1=n1; r2=n2; r3=n3; r4=n4; r5=n5; r6=n6; r7=n7; r8=n8;
            tx=q0; ty=q1; tz=q2;
        }
    }

    // ---- phase 2: Hillis-Steele scan over segment transforms (E stride 13) ----
    {
        float* e = buf + t * 13;
        e[0]=r0; e[1]=r1; e[2]=r2; e[3]=r3; e[4]=r4; e[5]=r5;
        e[6]=r6; e[7]=r7; e[8]=r8; e[9]=tx; e[10]=ty; e[11]=tz;
    }
    __syncthreads();

    #pragma unroll
    for (int l = 0; l < 4; ++l) {
        const int d = 1 << l;              // 1,2,4,8 (covers SEGS=14)
        const bool act = (s >= d);
        if (act) {
            const float* a = buf + (t - d) * 13;
            float A[12];
            #pragma unroll
            for (int w = 0; w < 12; ++w) A[w] = a[w];
            // X <- A * X  (A = earlier range, applied on the left)
            float n0 = A[0]*r0 + A[1]*r3 + A[2]*r6;
            float n1 = A[0]*r1 + A[1]*r4 + A[2]*r7;
            float n2 = A[0]*r2 + A[1]*r5 + A[2]*r8;
            float n3 = A[3]*r0 + A[4]*r3 + A[5]*r6;
            float n4 = A[3]*r1 + A[4]*r4 + A[5]*r7;
            float n5 = A[3]*r2 + A[4]*r5 + A[5]*r8;
            float n6 = A[6]*r0 + A[7]*r3 + A[8]*r6;
            float n7 = A[6]*r1 + A[7]*r4 + A[8]*r7;
            float n8 = A[6]*r2 + A[7]*r5 + A[8]*r8;
            float q0 = A[9]  + A[0]*tx + A[1]*ty + A[2]*tz;
            float q1 = A[10] + A[3]*tx + A[4]*ty + A[5]*tz;
            float q2 = A[11] + A[6]*tx + A[7]*ty + A[8]*tz;
            r0=n0; r1=n1; r2=n2; r3=n3; r4=n4; r5=n5; r6=n6; r7=n7; r8=n8;
            tx=q0; ty=q1; tz=q2;
        }
        __syncthreads();
        if (act) {
            float* e = buf + t * 13;
            e[0]=r0; e[1]=r1; e[2]=r2; e[3]=r3; e[4]=r4; e[5]=r5;
            e[6]=r6; e[7]=r7; e[8]=r8; e[9]=tx; e[10]=ty; e[11]=tz;
        }
        __syncthreads();
    }

    // ---- P = F0 (s==0) or F0 * incl_prefix[s-1] ----
    float P0,P1,P2,P3,P4,P5,P6,P7,P8, Pt0,Pt1,Pt2;
    {
        const float* f = F0[rl];
        if (s == 0) {
            P0=f[0]; P1=f[1]; P2=f[2];
            P3=f[3]; P4=f[4]; P5=f[5];
            P6=f[6]; P7=f[7]; P8=f[8];
            Pt0=f[9]; Pt1=f[10]; Pt2=f[11];
        } else {
            const float* b = buf + (t - 1) * 13;
            P0 = f[0]*b[0] + f[1]*b[3] + f[2]*b[6];
            P1 = f[0]*b[1] + f[1]*b[4] + f[2]*b[7];
            P2 = f[0]*b[2] + f[1]*b[5] + f[2]*b[8];
            P3 = f[3]*b[0] + f[4]*b[3] + f[5]*b[6];
            P4 = f[3]*b[1] + f[4]*b[4] + f[5]*b[7];
            P5 = f[3]*b[2] + f[4]*b[5] + f[5]*b[8];
            P6 = f[6]*b[0] + f[7]*b[3] + f[8]*b[6];
            P7 = f[6]*b[1] + f[7]*b[4] + f[8]*b[7];
            P8 = f[6]*b[2] + f[7]*b[5] + f[8]*b[8];
            Pt0 = f[9]  + f[0]*b[9] + f[1]*b[10] + f[2]*b[11];
            Pt1 = f[10] + f[3]*b[9] + f[4]*b[10] + f[5]*b[11];
            Pt2 = f[11] + f[6]*b[9] + f[7]*b[10] + f[8]*b[11];
        }
    }

    __syncthreads();   // all E/F0 reads retired; buf free for ST

    // ---- phase 3: G = P; G <- G o A_j; emit G.t into staging (no p[] array) ----
    {
        float* st = buf + rl * 378 + s * 27;
        #pragma unroll
        for (int j = 0; j < SLEN; ++j) {
            const int ph = j % 3;
            const float ca  = (ph==0)?ca0:(ph==1)?ca1:ca2;
            const float sa  = (ph==0)?sa0:(ph==1)?sa1:sa2;
            const float bca = (ph==0)?bc0:(ph==1)?bc1:bc2;
            const float bsa = (ph==0)?bs0:(ph==1)?bs1:bs2;

            float rr = __builtin_amdgcn_rsqf(sn[j]*sn[j] + cs[j]*cs[j] + 1e-8f);
            float st_ = sn[j]*rr, ct = cs[j]*rr;
            float m10=-sa*ct, m11=-ca*ct, m20=sa*st_, m21=ca*st_;
            float tl1=bsa*ct, tl2=-bsa*st_;

            // translation first (uses old R), then R <- R * M
            float q0 = Pt0 + P0*bca + P1*tl1 + P2*tl2;
            float q1 = Pt1 + P3*bca + P4*tl1 + P5*tl2;
            float q2 = Pt2 + P6*bca + P7*tl1 + P8*tl2;
            float n0 = P0*(-ca) + P1*m10 + P2*m20;
            float n1 = P0*sa    + P1*m11 + P2*m21;
            float n2 =            P1*st_ + P2*ct;
            float n3 = P3*(-ca) + P4*m10 + P5*m20;
            float n4 = P3*sa    + P4*m11 + P5*m21;
            float n5 =            P4*st_ + P5*ct;
            float n6 = P6*(-ca) + P7*m10 + P8*m20;
            float n7 = P6*sa    + P7*m11 + P8*m21;
            float n8 =            P7*st_ + P8*ct;
            P0=n0; P1=n1; P2=n2; P3=n3; P4=n4; P5=n5; P6=n6; P7=n7; P8=n8;
            Pt0=q0; Pt1=q1; Pt2=q2;

            st[3*j+0] = q0; st[3*j+1] = q1; st[3*j+2] = q2;
        }
    }

    __syncthreads();   // ST slab ready

    // ---- block-dense coalesced store ----
    #pragma unroll
    for (int i = 0; i < 27; ++i)
        out[gout + i * TPB + t] = buf[i * TPB + t];
}

extern "C" void kernel_launch(void* const* d_in, const int* in_sizes, int n_in,
                              void* d_out, int out_size, void* d_ws, size_t ws_size,
                              hipStream_t stream)
{
    const float* angles = (const float*)d_in[0];
    const float* prev   = (const float*)d_in[1];
    float*       out    = (float*)d_out;

    int nrows = in_sizes[1] / 9;            // B = 65536
    int grid  = (nrows + RPB - 1) / RPB;    // 2048 blocks x 7 waves

    DihedralToCartesian_kernel<<<grid, TPB, 0, stream>>>(angles, prev, out, nrows);
}